// Round 8
// baseline (100.299 us; speedup 1.0000x reference)
//
#include <hip/hip_runtime.h>
#include <hip/hip_bf16.h>
#include <math.h>

#define NPIX 4096

typedef __attribute__((ext_vector_type(8))) short s8;    // 8 x bf16 (4 VGPRs)
typedef __attribute__((ext_vector_type(16))) float f16v; // 16 x f32 (32x32 acc)

typedef __attribute__((address_space(1))) const void glob_cv;
typedef __attribute__((address_space(3))) void lds_v;

static __device__ __forceinline__ unsigned packbf2(float a, float b) {
    union { __hip_bfloat162 h; unsigned u; } x;
    x.h = __float22bfloat162_rn(make_float2(a, b));
    return x.u;
}
static __device__ __forceinline__ float fexp2(float x) {
#if __has_builtin(__builtin_amdgcn_exp2f)
    return __builtin_amdgcn_exp2f(x);
#else
    return exp2f(x);
#endif
}

// async global->LDS 16B: HW writes lane l at (wave-uniform lds base) + l*16.
static __device__ __forceinline__ void gl_lds16(const unsigned short* g,
                                                unsigned short* l, int lane) {
#if __has_builtin(__builtin_amdgcn_global_load_lds)
    __builtin_amdgcn_global_load_lds((glob_cv*)g, (lds_v*)l, 16, 0, 0);
#else
    *(uint4*)(l + lane * 8) = *(const uint4*)g;   // correctness fallback (sync)
#endif
}

// Half-swap of two regs across the lane<32 / lane>=32 boundary.
static __device__ __forceinline__ void lane_swap(unsigned a, unsigned b, int lh,
                                                 unsigned &x, unsigned &y) {
#if __has_builtin(__builtin_amdgcn_permlane32_swap)
    auto r = __builtin_amdgcn_permlane32_swap((int)a, (int)b, false, false);
    x = (unsigned)r[0];
    y = (unsigned)r[1];
#else
    unsigned sa = __shfl_xor(a, 32), sb = __shfl_xor(b, 32);
    x = lh ? sb : a;
    y = lh ? b : sa;
#endif
}

// ---------------------------------------------------------------------------
// Kernel 1: prep v2 (unchanged; R3-R7 passed).
// ---------------------------------------------------------------------------
__global__ __launch_bounds__(512) void prep_kernel(
    const float* __restrict__ x,
    const float* __restrict__ Wq, const float* __restrict__ bq,
    const float* __restrict__ Wk, const float* __restrict__ bk,
    __hip_bfloat16* __restrict__ qbf, __hip_bfloat16* __restrict__ kbf,
    __hip_bfloat16* __restrict__ xbf)
{
    __shared__ float Xp[64][65];
    __shared__ unsigned short Qs[64][8];
    int t = threadIdx.x;
    int p = t & 63;                  // pixel lane
    int g = t >> 6;                  // 0..7 = output channel (wave-uniform)
    int bid = blockIdx.x;
    int og = bid & 1;                // 0: q, 1: k
    int n0 = ((bid >> 1) & 63) << 6;
    int b  = bid >> 7;

    const float* xb = x + ((size_t)b << 18);
    __hip_bfloat16* xbb = xbf + ((size_t)b << 18);
#pragma unroll
    for (int u = 0; u < 8; ++u) {
        int c = g + (u << 3);
        float v = xb[((size_t)c << 12) + n0 + p];
        Xp[c][p] = v;
        if ((og == 0) ? (u < 4) : (u >= 4))   // split conversion halves
            xbb[((size_t)c << 12) + n0 + p] = __float2bfloat16(v);
    }
    __syncthreads();

    const float* W  = og ? Wk : Wq;
    const float* bb = og ? bk : bq;
    const float* wr = W + g * 64;            // wave-uniform row
    float acc = bb[g];
#pragma unroll
    for (int c = 0; c < 64; ++c) acc = fmaf(wr[c], Xp[c][p], acc);
    if (!og) acc *= 1.4426950408889634f;     // fold log2(e) into q

    union { __hip_bfloat16 h; unsigned short u; } cv;
    cv.h = __float2bfloat16(acc);
    Qs[p][g] = cv.u;
    __syncthreads();

    if (t < 64) {
        __hip_bfloat16* dst = (og ? kbf : qbf) + ((size_t)(b * NPIX + n0 + t) << 3);
        *(s8*)dst = *(const s8*)&Qs[t][0];   // coalesced 16B per pixel
    }
}

// ---------------------------------------------------------------------------
// Kernel 2: fused flash, R8.
// DIAGNOSIS (R5==R6==R7 ~30us regardless of sync structure): L2-BW bound.
// Each block reads its batch's whole X (2MB): 512 blk x 2MB = 1GB through
// L2; per XCD 128MB / ~4.3TB/s = 30us. FIX: 64-i blocks (256 total) ->
// X traffic halves (15us floor). Same wave j-ownership; per sub-tile TWO
// score/softmax pipelines (i-halves) share ONE X staging; X fragments
// loaded once feed both i-halves' PV MFMAs. acc = 4 named f16v (rule #20).
// __launch_bounds__(512,2): VGPR cap 256 (R1 spill excluded); 1 blk/CU.
// RACE FIX (R7 absmax 0.0615->0.083): prologue was one sched region; the
// compiler could reorder B1's DMAs ahead of A0's, making WAITN(5) retire
// the wrong set -> tile-0 reads before landing. Prologue now fenced into
// ordered regions via sched_barrier(0). Steady-state regions are
// permutation-safe (retire-set = whole region of exactly 5 VMEM ops).
// ---------------------------------------------------------------------------
__global__ __launch_bounds__(512, 2) void flash_fused_kernel(
    const __hip_bfloat16* __restrict__ qbf, const __hip_bfloat16* __restrict__ kbf,
    const __hip_bfloat16* __restrict__ xbf,
    const float* __restrict__ Wv, const float* __restrict__ bv,
    const float* __restrict__ x, const float* __restrict__ gamma,
    float* __restrict__ out)
{
    // main loop: wave w owns pool[w*8192 .. +8191]: 2 x 4096 B buffers,
    //   each [64 rows][4 granules of 16 B], granule-XOR-swizzled.
    // epilogue overlay (after full __syncthreads): OshA [32][68] @0 |
    //   OshB @8704 | Linv @17408 | bvs @17536 | Wvs @17792 (16384) | Lsh @34176
    __shared__ __align__(16) char pool[65536];

    int t = threadIdx.x;
    int w    = t >> 6;               // 0..7 = j-range owner (wave-uniform)
    int lane = t & 63;
    int l32  = lane & 31;
    int lh   = lane >> 5;

    // bijective XCD-contiguous remap (8 XCDs, 256 blocks)
    int bid  = blockIdx.x;
    int lbid = ((bid & 7) << 5) + (bid >> 3);
    int b  = lbid >> 6;
    int i0 = (lbid & 63) << 6;       // 64-i tile

    const s8 zero8 = {0, 0, 0, 0, 0, 0, 0, 0};

    // Q B-frags for both i-halves (lh=1 half zeroed: d<8)
    s8 qf0, qf1;
    {
        s8 qv0 = *(const s8*)(qbf + ((size_t)(b * NPIX + i0 + l32) << 3));
        s8 qv1 = *(const s8*)(qbf + ((size_t)(b * NPIX + i0 + 32 + l32) << 3));
        qf0 = (lh == 0) ? qv0 : zero8;
        qf1 = (lh == 0) ? qv1 : zero8;
    }

    // acc<ih><cm>: O[c = cm*32+row(r,lh)][i = i0 + ih*32 + l32]
    f16v acc00, acc01, acc10, acc11, zero16;
#pragma unroll
    for (int r = 0; r < 16; ++r) {
        acc00[r] = 0.f; acc01[r] = 0.f; acc10[r] = 0.f; acc11[r] = 0.f;
        zero16[r] = 0.f;
    }
    float lsum0 = 0.f, lsum1 = 0.f;

    const __hip_bfloat16* kb = kbf + ((size_t)(b * NPIX) << 3) + ((size_t)(w << 9) << 3);
    const unsigned short* xg = (const unsigned short*)xbf + ((size_t)b << 18);

    unsigned short* mybuf = (unsigned short*)pool + (w << 12);  // 8192 B/wave

    // DMA u (0..3): lane l -> row = 16u + (l>>2), phys granule l&3, sourced
    // from global granule (l&3)^swz(row), swz = (row>>1)&3. Linear LDS dest.
    int l2 = lane >> 2, lg = lane & 3;
    int srcb[4];                      // shorts; + n*32 per sub-tile
#pragma unroll
    for (int u = 0; u < 4; ++u) {
        int row = (u << 4) + l2;
        srcb[u] = (row << 12) + (w << 9) + ((lg ^ ((row >> 1) & 3)) << 3);
    }
    // PV b128 read offsets (shorts, loop-invariant)
    int sw = (l32 >> 1) & 3;
    int o00 = (l32 << 5) + ((lh ^ sw) << 3);
    int o01 = (l32 << 5) + (((2 + lh) ^ sw) << 3);
    int o10 = ((32 + l32) << 5) + ((lh ^ sw) << 3);
    int o11 = ((32 + l32) << 5) + (((2 + lh) ^ sw) << 3);

#define STAGE(BO, N) do {                                                    \
        unsigned short* lb_ = mybuf + (BO);                                  \
        _Pragma("unroll")                                                    \
        for (int u_ = 0; u_ < 4; ++u_)                                       \
            gl_lds16(xg + srcb[u_] + ((N) << 5), lb_ + (u_ << 9), lane);     \
    } while (0)

#define WAITN(N) do {                                                        \
        asm volatile("s_waitcnt vmcnt(" #N ")" ::: "memory");                \
        __builtin_amdgcn_sched_barrier(0);                                   \
    } while (0)

// softmax of one score frag -> packed bf16 pairs + l-sum
#define SM(SC, LS, P2) do {                                                  \
        float e_[16];                                                        \
        _Pragma("unroll")                                                    \
        for (int r_ = 0; r_ < 16; ++r_) e_[r_] = fexp2((SC)[r_]);            \
        _Pragma("unroll")                                                    \
        for (int r_ = 0; r_ < 16; ++r_) (LS) += e_[r_];                      \
        _Pragma("unroll")                                                    \
        for (int s_ = 0; s_ < 8; ++s_) (P2)[s_] = packbf2(e_[2*s_], e_[2*s_+1]); \
    } while (0)

// build the two K=16 B-frags (j 0..15 / 16..31) from packed pairs
#define MKBF(P2, BF0, BF1) do {                                              \
        unsigned c0,c1,c2,c3,c4,c5,c6,c7;                                    \
        lane_swap((P2)[0], (P2)[2], lh, c0, c2);                             \
        lane_swap((P2)[1], (P2)[3], lh, c1, c3);                             \
        lane_swap((P2)[4], (P2)[6], lh, c4, c6);                             \
        lane_swap((P2)[5], (P2)[7], lh, c5, c7);                             \
        (BF0).u[0]=c0; (BF0).u[1]=c1; (BF0).u[2]=c2; (BF0).u[3]=c3;          \
        (BF1).u[0]=c4; (BF1).u[1]=c5; (BF1).u[2]=c6; (BF1).u[3]=c7;          \
    } while (0)

#define BODY2(BO, KF) do {                                                   \
        f16v sC0 = __builtin_amdgcn_mfma_f32_32x32x16_bf16(KF, qf0, zero16, 0, 0, 0); \
        f16v sC1 = __builtin_amdgcn_mfma_f32_32x32x16_bf16(KF, qf1, zero16, 0, 0, 0); \
        union { unsigned u[4]; s8 v; } bfA0, bfA1, bfB0, bfB1;               \
        { unsigned P2[8]; SM(sC0, lsum0, P2); MKBF(P2, bfA0, bfA1); }        \
        { unsigned P2[8]; SM(sC1, lsum1, P2); MKBF(P2, bfB0, bfB1); }        \
        const unsigned short* xb_ = mybuf + (BO);                            \
        s8 xa;                                                               \
        xa = *(const s8*)(xb_ + o00);                                        \
        acc00 = __builtin_amdgcn_mfma_f32_32x32x16_bf16(xa, bfA0.v, acc00, 0, 0, 0); \
        acc10 = __builtin_amdgcn_mfma_f32_32x32x16_bf16(xa, bfB0.v, acc10, 0, 0, 0); \
        xa = *(const s8*)(xb_ + o01);                                        \
        acc00 = __builtin_amdgcn_mfma_f32_32x32x16_bf16(xa, bfA1.v, acc00, 0, 0, 0); \
        acc10 = __builtin_amdgcn_mfma_f32_32x32x16_bf16(xa, bfB1.v, acc10, 0, 0, 0); \
        xa = *(const s8*)(xb_ + o10);                                        \
        acc01 = __builtin_amdgcn_mfma_f32_32x32x16_bf16(xa, bfA0.v, acc01, 0, 0, 0); \
        acc11 = __builtin_amdgcn_mfma_f32_32x32x16_bf16(xa, bfB0.v, acc11, 0, 0, 0); \
        xa = *(const s8*)(xb_ + o11);                                        \
        acc01 = __builtin_amdgcn_mfma_f32_32x32x16_bf16(xa, bfA1.v, acc01, 0, 0, 0); \
        acc11 = __builtin_amdgcn_mfma_f32_32x32x16_bf16(xa, bfB1.v, acc11, 0, 0, 0); \
    } while (0)

    // prologue: FENCED regions so VMEM issue order is compiler-proof:
    // [qf0,qf1] | [kfA, A(0)x4] | [kfB, B(1)x4]  -> first WAITN(5) retires
    // exactly {qf0,qf1,kfA,A(0)x4}.
    __builtin_amdgcn_sched_barrier(0);
    s8 kfA = *(const s8*)(kb + ((size_t)l32 << 3));
    STAGE(0, 0);
    __builtin_amdgcn_sched_barrier(0);
    s8 kfB = *(const s8*)(kb + ((size_t)(32 + l32) << 3));
    STAGE(2048, 1);

    // steady state: every region issues exactly 5 VMEM ops {kf, 4 DMA};
    // WAITN(5) == "everything before the previous region is retired".
    for (int n = 0; n < 14; n += 2) {
        WAITN(5);                     // A(n) + kfA landed (staged 1 body ago)
        BODY2(0, kfA);
        kfA = *(const s8*)(kb + ((size_t)(((n + 2) << 5) + l32) << 3));
        STAGE(0, n + 2);
        WAITN(5);                     // B(n+1) + kfB landed
        BODY2(2048, kfB);
        kfB = *(const s8*)(kb + ((size_t)(((n + 3) << 5) + l32) << 3));
        STAGE(2048, n + 3);
    }
    WAITN(5);                         // A(14) landed
    BODY2(0, kfA);
    WAITN(0);                         // B(15) landed
    BODY2(2048, kfB);
#undef BODY2
#undef MKBF
#undef SM
#undef WAITN
#undef STAGE

    // ---------------- epilogue (cross-wave; barriers resume here) ----------
    float* OshA = (float*)pool;                  // [32 i][68]
    float* OshB = (float*)(pool + 8704);         // [32 i][68]
    float* Linv = (float*)(pool + 17408);        // [32]
    float* bvs  = (float*)(pool + 17536);        // [64]
    float* Wvs  = (float*)(pool + 17792);        // [64][64]
    float* Lsh  = (float*)(pool + 34176);        // [8][32]

    lsum0 += __shfl_xor(lsum0, 32);              // full 512-j sums per i
    lsum1 += __shfl_xor(lsum1, 32);
    __syncthreads();                 // ALL waves done with private regions

    float g = gamma[0];
    const float* xr = x + ((size_t)b << 18) + i0;
    float* outp = out + ((size_t)b << 18) + i0;

    // one epilogue pass per i-half, reusing the shared buffers
    auto epi = [&](f16v& a0, f16v& a1, float ls, int ih) {
        if (ih) __syncthreads();     // previous half's projection done
        if (lh == 0) Lsh[w * 32 + l32] = ls;

        float* Og = (w >> 2) ? OshB : OshA;
        for (int s = 0; s < 4; ++s) {
            __syncthreads();
            if ((w & 3) == s) {
#pragma unroll
                for (int cm = 0; cm < 2; ++cm) {
                    f16v& ac = cm ? a1 : a0;
#pragma unroll
                    for (int r = 0; r < 16; ++r) {
                        int cc = cm * 32 + (r & 3) + 8 * (r >> 2) + 4 * lh;
                        float* p = Og + l32 * 68 + cc;
                        if (s == 0) *p = ac[r];
                        else        *p += ac[r];
                    }
                }
            }
        }
        __syncthreads();

        if (t < 32) {
            float lt = 0.f;
#pragma unroll
            for (int ww = 0; ww < 8; ++ww) lt += Lsh[ww * 32 + t];
            Linv[t] = 1.0f / lt;
        }
        if (ih == 0) {
            if (t < 64) bvs[t] = bv[t];
            const float4* wsrc = (const float4*)Wv;
            float4* wdst = (float4*)Wvs;
            wdst[t] = wsrc[t];
            wdst[t + 512] = wsrc[t + 512];
        }
        __syncthreads();

        // projection + residual for rows i0+ih*32 .. +31
        int i  = t & 31;
        int cg = t >> 5;
        float inv = Linv[i];
        float res[4] = {0.f, 0.f, 0.f, 0.f};
#pragma unroll 4
        for (int cb = 0; cb < 16; ++cb) {
            float4 oa = *(const float4*)(OshA + i * 68 + cb * 4);
            float4 ob = *(const float4*)(OshB + i * 68 + cb * 4);
            float4 o = make_float4(oa.x + ob.x, oa.y + ob.y, oa.z + ob.z, oa.w + ob.w);
#pragma unroll
            for (int k = 0; k < 4; ++k) {
                const float4 wv4 = *(const float4*)(Wvs + (cg * 4 + k) * 64 + cb * 4);
                res[k] = fmaf(wv4.x, o.x, fmaf(wv4.y, o.y, fmaf(wv4.z, o.z, fmaf(wv4.w, o.w, res[k]))));
            }
        }
#pragma unroll
        for (int k = 0; k < 4; ++k) {
            int cch = cg * 4 + k;
            float attn = fmaf(res[k], inv, bvs[cch]);
            size_t off = ((size_t)cch << 12) + (ih << 5) + i;
            outp[off] = fmaf(g, attn, xr[off]);
        }
    };

    epi(acc00, acc01, lsum0, 0);
    epi(acc10, acc11, lsum1, 1);
}

extern "C" void kernel_launch(void* const* d_in, const int* in_sizes, int n_in,
                              void* d_out, int out_size, void* d_ws, size_t ws_size,
                              hipStream_t stream) {
    const float* x     = (const float*)d_in[0];
    const float* Wq    = (const float*)d_in[1];
    const float* bq    = (const float*)d_in[2];
    const float* Wk    = (const float*)d_in[3];
    const float* bk    = (const float*)d_in[4];
    const float* Wv    = (const float*)d_in[5];
    const float* bv    = (const float*)d_in[6];
    const float* gamma = (const float*)d_in[7];
    float* out = (float*)d_out;

    // ws: qbf 256KB | kbf 256KB | xbf 2MB
    __hip_bfloat16* qbf = (__hip_bfloat16*)d_ws;
    __hip_bfloat16* kbf = qbf + (size_t)4 * NPIX * 8;
    __hip_bfloat16* xbf = kbf + (size_t)4 * NPIX * 8;

    prep_kernel<<<512, 512, 0, stream>>>(x, Wq, bq, Wk, bk, qbf, kbf, xbf);
    flash_fused_kernel<<<256, 512, 0, stream>>>(qbf, kbf, xbf, Wv, bv, x, gamma, out);
}

// Round 10
// 99.544 us; speedup vs baseline: 1.0076x; 1.0076x over previous
//
#include <hip/hip_runtime.h>
#include <hip/hip_bf16.h>
#include <math.h>

#define NPIX 4096

typedef __attribute__((ext_vector_type(8))) short s8;    // 8 x bf16 (4 VGPRs)
typedef __attribute__((ext_vector_type(4))) unsigned u4; // 4 x u32  (4 VGPRs)
typedef __attribute__((ext_vector_type(16))) float f16v; // 16 x f32 (32x32 acc)

typedef __attribute__((address_space(1))) const void glob_cv;
typedef __attribute__((address_space(3))) void lds_v;

static __device__ __forceinline__ unsigned packbf2(float a, float b) {
    union { __hip_bfloat162 h; unsigned u; } x;
    x.h = __float22bfloat162_rn(make_float2(a, b));
    return x.u;
}
static __device__ __forceinline__ float fexp2(float x) {
#if __has_builtin(__builtin_amdgcn_exp2f)
    return __builtin_amdgcn_exp2f(x);
#else
    return exp2f(x);
#endif
}

// async global->LDS 16B: HW writes lane l at (wave-uniform lds base) + l*16.
static __device__ __forceinline__ void gl_lds16(const unsigned short* g,
                                                unsigned short* l, int lane) {
#if __has_builtin(__builtin_amdgcn_global_load_lds)
    __builtin_amdgcn_global_load_lds((glob_cv*)g, (lds_v*)l, 16, 0, 0);
#else
    *(uint4*)(l + lane * 8) = *(const uint4*)g;   // correctness fallback (sync)
#endif
}

// Inline-asm ds_read_b128: INVISIBLE to the compiler's alias analysis, so it
// cannot insert a conservative `s_waitcnt vmcnt(0)` guard against the LDS-DMA
// (theory: that auto-guard was the recurring ~4000-cyc stall making
// R6(sync waits) == R7(counted) == R8 at ~30us). Output hardened to the
// canonical v4i32 tuple with early-clobber (R9's s8 output was the only
// novel construct in the twice-failed build). Caller must fence with
// lgkmcnt(0) + sched_barrier(0) before consuming (rule #18).
static __device__ __forceinline__ u4 ds128(unsigned byte_addr) {
    u4 r;
    asm volatile("ds_read_b128 %0, %1" : "=&v"(r) : "v"(byte_addr));
    return r;
}

// Half-swap of two regs across the lane<32 / lane>=32 boundary.
static __device__ __forceinline__ void lane_swap(unsigned a, unsigned b, int lh,
                                                 unsigned &x, unsigned &y) {
#if __has_builtin(__builtin_amdgcn_permlane32_swap)
    auto r = __builtin_amdgcn_permlane32_swap((int)a, (int)b, false, false);
    x = (unsigned)r[0];
    y = (unsigned)r[1];
#else
    unsigned sa = __shfl_xor(a, 32), sb = __shfl_xor(b, 32);
    x = lh ? sb : a;
    y = lh ? b : sa;
#endif
}

// ---------------------------------------------------------------------------
// Kernel 1: prep v2 (unchanged; R3-R8 passed).
// ---------------------------------------------------------------------------
__global__ __launch_bounds__(512) void prep_kernel(
    const float* __restrict__ x,
    const float* __restrict__ Wq, const float* __restrict__ bq,
    const float* __restrict__ Wk, const float* __restrict__ bk,
    __hip_bfloat16* __restrict__ qbf, __hip_bfloat16* __restrict__ kbf,
    __hip_bfloat16* __restrict__ xbf)
{
    __shared__ float Xp[64][65];
    __shared__ unsigned short Qs[64][8];
    int t = threadIdx.x;
    int p = t & 63;                  // pixel lane
    int g = t >> 6;                  // 0..7 = output channel (wave-uniform)
    int bid = blockIdx.x;
    int og = bid & 1;                // 0: q, 1: k
    int n0 = ((bid >> 1) & 63) << 6;
    int b  = bid >> 7;

    const float* xb = x + ((size_t)b << 18);
    __hip_bfloat16* xbb = xbf + ((size_t)b << 18);
#pragma unroll
    for (int u = 0; u < 8; ++u) {
        int c = g + (u << 3);
        float v = xb[((size_t)c << 12) + n0 + p];
        Xp[c][p] = v;
        if ((og == 0) ? (u < 4) : (u >= 4))   // split conversion halves
            xbb[((size_t)c << 12) + n0 + p] = __float2bfloat16(v);
    }
    __syncthreads();

    const float* W  = og ? Wk : Wq;
    const float* bb = og ? bk : bq;
    const float* wr = W + g * 64;            // wave-uniform row
    float acc = bb[g];
#pragma unroll
    for (int c = 0; c < 64; ++c) acc = fmaf(wr[c], Xp[c][p], acc);
    if (!og) acc *= 1.4426950408889634f;     // fold log2(e) into q

    union { __hip_bfloat16 h; unsigned short u; } cv;
    cv.h = __float2bfloat16(acc);
    Qs[p][g] = cv.u;
    __syncthreads();

    if (t < 64) {
        __hip_bfloat16* dst = (og ? kbf : qbf) + ((size_t)(b * NPIX + n0 + t) << 3);
        *(s8*)dst = *(const s8*)&Qs[t][0];   // coalesced 16B per pixel
    }
}

// ---------------------------------------------------------------------------
// Kernel 2: fused flash, R10 = R9 resubmit (container died twice before
// producing results — suspected infra flake or ICE on the novel asm operand
// form). Changes vs R9: ds128 output is canonical v4i32 + early-clobber;
// union bit-cast to s8 at use. Geometry/waits/math/epilogue identical.
// THEORY (untested): compiler alias-guards visible ds_reads of DMA-written
// LDS with its own vmcnt(0), draining the just-issued STAGE every body
// (the ~4000 cyc/BODY2 stall). Asm reads remove the visible alias; counted
// vmcnt(5) becomes the only wait; lgkmcnt(0)+sched_barrier(0) fences the
// PV MFMAs (rule #18).
// ---------------------------------------------------------------------------
__global__ __launch_bounds__(512, 2) void flash_fused_kernel(
    const __hip_bfloat16* __restrict__ qbf, const __hip_bfloat16* __restrict__ kbf,
    const __hip_bfloat16* __restrict__ xbf,
    const float* __restrict__ Wv, const float* __restrict__ bv,
    const float* __restrict__ x, const float* __restrict__ gamma,
    float* __restrict__ out)
{
    // main loop: wave w owns pool[w*8192 .. +8191]: 2 x 4096 B buffers,
    //   each [64 rows][4 granules of 16 B], granule-XOR-swizzled.
    // epilogue overlay (after full __syncthreads): OshA [32][68] @0 |
    //   OshB @8704 | Linv @17408 | bvs @17536 | Wvs @17792 (16384) | Lsh @34176
    __shared__ __align__(16) char pool[65536];

    int t = threadIdx.x;
    int w    = t >> 6;               // 0..7 = j-range owner (wave-uniform)
    int lane = t & 63;
    int l32  = lane & 31;
    int lh   = lane >> 5;

    // bijective XCD-contiguous remap (8 XCDs, 256 blocks)
    int bid  = blockIdx.x;
    int lbid = ((bid & 7) << 5) + (bid >> 3);
    int b  = lbid >> 6;
    int i0 = (lbid & 63) << 6;       // 64-i tile

    const s8 zero8 = {0, 0, 0, 0, 0, 0, 0, 0};

    // Q B-frags for both i-halves (lh=1 half zeroed: d<8)
    s8 qf0, qf1;
    {
        s8 qv0 = *(const s8*)(qbf + ((size_t)(b * NPIX + i0 + l32) << 3));
        s8 qv1 = *(const s8*)(qbf + ((size_t)(b * NPIX + i0 + 32 + l32) << 3));
        qf0 = (lh == 0) ? qv0 : zero8;
        qf1 = (lh == 0) ? qv1 : zero8;
    }

    // acc<ih><cm>: O[c = cm*32+row(r,lh)][i = i0 + ih*32 + l32]
    f16v acc00, acc01, acc10, acc11, zero16;
#pragma unroll
    for (int r = 0; r < 16; ++r) {
        acc00[r] = 0.f; acc01[r] = 0.f; acc10[r] = 0.f; acc11[r] = 0.f;
        zero16[r] = 0.f;
    }
    float lsum0 = 0.f, lsum1 = 0.f;

    const __hip_bfloat16* kb = kbf + ((size_t)(b * NPIX) << 3) + ((size_t)(w << 9) << 3);
    const unsigned short* xg = (const unsigned short*)xbf + ((size_t)b << 18);

    unsigned short* mybuf = (unsigned short*)pool + (w << 12);  // 8192 B/wave
    unsigned ldsbase = (unsigned)(uintptr_t)(lds_v*)mybuf;      // LDS byte addr

    // DMA u (0..3): lane l -> row = 16u + (l>>2), phys granule l&3, sourced
    // from global granule (l&3)^swz(row), swz = (row>>1)&3. Linear LDS dest.
    int l2 = lane >> 2, lg = lane & 3;
    int srcb[4];                      // shorts; + n*32 per sub-tile
#pragma unroll
    for (int u = 0; u < 4; ++u) {
        int row = (u << 4) + l2;
        srcb[u] = (row << 12) + (w << 9) + ((lg ^ ((row >> 1) & 3)) << 3);
    }
    // PV b128 read BYTE offsets (loop-invariant)
    int sw = (l32 >> 1) & 3;
    unsigned o00b = (unsigned)(((l32 << 5) + ((lh ^ sw) << 3)) << 1);
    unsigned o01b = (unsigned)(((l32 << 5) + (((2 + lh) ^ sw) << 3)) << 1);
    unsigned o10b = (unsigned)((((32 + l32) << 5) + ((lh ^ sw) << 3)) << 1);
    unsigned o11b = (unsigned)((((32 + l32) << 5) + (((2 + lh) ^ sw) << 3)) << 1);

#define STAGE(BO, N) do {                                                    \
        unsigned short* lb_ = mybuf + (BO);                                  \
        _Pragma("unroll")                                                    \
        for (int u_ = 0; u_ < 4; ++u_)                                       \
            gl_lds16(xg + srcb[u_] + ((N) << 5), lb_ + (u_ << 9), lane);     \
    } while (0)

#define WAITN(N) do {                                                        \
        asm volatile("s_waitcnt vmcnt(" #N ")" ::: "memory");                \
        __builtin_amdgcn_sched_barrier(0);                                   \
    } while (0)

// softmax of one score frag -> packed bf16 pairs + l-sum
#define SM(SC, LS, P2) do {                                                  \
        float e_[16];                                                        \
        _Pragma("unroll")                                                    \
        for (int r_ = 0; r_ < 16; ++r_) e_[r_] = fexp2((SC)[r_]);            \
        _Pragma("unroll")                                                    \
        for (int r_ = 0; r_ < 16; ++r_) (LS) += e_[r_];                      \
        _Pragma("unroll")                                                    \
        for (int s_ = 0; s_ < 8; ++s_) (P2)[s_] = packbf2(e_[2*s_], e_[2*s_+1]); \
    } while (0)

// build the two K=16 B-frags (j 0..15 / 16..31) from packed pairs
#define MKBF(P2, BF0, BF1) do {                                              \
        unsigned c0,c1,c2,c3,c4,c5,c6,c7;                                    \
        lane_swap((P2)[0], (P2)[2], lh, c0, c2);                             \
        lane_swap((P2)[1], (P2)[3], lh, c1, c3);                             \
        lane_swap((P2)[4], (P2)[6], lh, c4, c6);                             \
        lane_swap((P2)[5], (P2)[7], lh, c5, c7);                             \
        (BF0).u[0]=c0; (BF0).u[1]=c1; (BF0).u[2]=c2; (BF0).u[3]=c3;          \
        (BF1).u[0]=c4; (BF1).u[1]=c5; (BF1).u[2]=c6; (BF1).u[3]=c7;          \
    } while (0)

#define BODY2(BO, KF) do {                                                   \
        /* asm LDS reads first: ~120cy latency hides under score+softmax */  \
        unsigned ab_ = ldsbase + ((unsigned)(BO) << 1);                      \
        union { u4 q; s8 v; } xa00, xa01, xa10, xa11;                        \
        xa00.q = ds128(ab_ + o00b);                                          \
        xa01.q = ds128(ab_ + o01b);                                          \
        xa10.q = ds128(ab_ + o10b);                                          \
        xa11.q = ds128(ab_ + o11b);                                          \
        f16v sC0 = __builtin_amdgcn_mfma_f32_32x32x16_bf16(KF, qf0, zero16, 0, 0, 0); \
        f16v sC1 = __builtin_amdgcn_mfma_f32_32x32x16_bf16(KF, qf1, zero16, 0, 0, 0); \
        union { unsigned u[4]; s8 v; } bfA0, bfA1, bfB0, bfB1;               \
        { unsigned P2[8]; SM(sC0, lsum0, P2); MKBF(P2, bfA0, bfA1); }        \
        { unsigned P2[8]; SM(sC1, lsum1, P2); MKBF(P2, bfB0, bfB1); }        \
        asm volatile("s_waitcnt lgkmcnt(0)" ::: "memory");                   \
        __builtin_amdgcn_sched_barrier(0);   /* rule #18: pin MFMAs after */ \
        acc00 = __builtin_amdgcn_mfma_f32_32x32x16_bf16(xa00.v, bfA0.v, acc00, 0, 0, 0); \
        acc10 = __builtin_amdgcn_mfma_f32_32x32x16_bf16(xa00.v, bfB0.v, acc10, 0, 0, 0); \
        acc00 = __builtin_amdgcn_mfma_f32_32x32x16_bf16(xa01.v, bfA1.v, acc00, 0, 0, 0); \
        acc10 = __builtin_amdgcn_mfma_f32_32x32x16_bf16(xa01.v, bfB1.v, acc10, 0, 0, 0); \
        acc01 = __builtin_amdgcn_mfma_f32_32x32x16_bf16(xa10.v, bfA0.v, acc01, 0, 0, 0); \
        acc11 = __builtin_amdgcn_mfma_f32_32x32x16_bf16(xa10.v, bfB0.v, acc11, 0, 0, 0); \
        acc01 = __builtin_amdgcn_mfma_f32_32x32x16_bf16(xa11.v, bfA1.v, acc01, 0, 0, 0); \
        acc11 = __builtin_amdgcn_mfma_f32_32x32x16_bf16(xa11.v, bfB1.v, acc11, 0, 0, 0); \
    } while (0)

    // prologue: FENCED regions so VMEM issue order is compiler-proof:
    // [qf0,qf1] | [kfA, A(0)x4] | [kfB, B(1)x4]  -> first WAITN(5) retires
    // exactly {qf0,qf1,kfA,A(0)x4}.  (R8 race fix — keep.)
    __builtin_amdgcn_sched_barrier(0);
    s8 kfA = *(const s8*)(kb + ((size_t)l32 << 3));
    STAGE(0, 0);
    __builtin_amdgcn_sched_barrier(0);
    s8 kfB = *(const s8*)(kb + ((size_t)(32 + l32) << 3));
    STAGE(2048, 1);

    // steady state: every region issues exactly 5 VMEM ops {kf, 4 DMA};
    // WAITN(5) == "everything before the previous region is retired".
    for (int n = 0; n < 14; n += 2) {
        WAITN(5);                     // A(n) + kfA landed (staged 1 body ago)
        BODY2(0, kfA);
        kfA = *(const s8*)(kb + ((size_t)(((n + 2) << 5) + l32) << 3));
        STAGE(0, n + 2);
        WAITN(5);                     // B(n+1) + kfB landed
        BODY2(2048, kfB);
        kfB = *(const s8*)(kb + ((size_t)(((n + 3) << 5) + l32) << 3));
        STAGE(2048, n + 3);
    }
    WAITN(5);                         // A(14) landed
    BODY2(0, kfA);
    WAITN(0);                         // B(15) landed
    BODY2(2048, kfB);
#undef BODY2
#undef MKBF
#undef SM
#undef WAITN
#undef STAGE

    // ---------------- epilogue (cross-wave; barriers resume here) ----------
    float* OshA = (float*)pool;                  // [32 i][68]
    float* OshB = (float*)(pool + 8704);         // [32 i][68]
    float* Linv = (float*)(pool + 17408);        // [32]
    float* bvs  = (float*)(pool + 17536);        // [64]
    float* Wvs  = (float*)(pool + 17792);        // [64][64]
    float* Lsh  = (float*)(pool + 34176);        // [8][32]

    lsum0 += __shfl_xor(lsum0, 32);              // full 512-j sums per i
    lsum1 += __shfl_xor(lsum1, 32);
    __syncthreads();                 // ALL waves done with private regions

    float g = gamma[0];
    const float* xr = x + ((size_t)b << 18) + i0;
    float* outp = out + ((size_t)b << 18) + i0;

    // one epilogue pass per i-half, reusing the shared buffers
    auto epi = [&](f16v& a0, f16v& a1, float ls, int ih) {
        if (ih) __syncthreads();     // previous half's projection done
        if (lh == 0) Lsh[w * 32 + l32] = ls;

        float* Og = (w >> 2) ? OshB : OshA;
        for (int s = 0; s < 4; ++s) {
            __syncthreads();
            if ((w & 3) == s) {
#pragma unroll
                for (int cm = 0; cm < 2; ++cm) {
                    f16v& ac = cm ? a1 : a0;
#pragma unroll
                    for (int r = 0; r < 16; ++r) {
                        int cc = cm * 32 + (r & 3) + 8 * (r >> 2) + 4 * lh;
                        float* p = Og + l32 * 68 + cc;
                        if (s == 0) *p = ac[r];
                        else        *p += ac[r];
                    }
                }
            }
        }
        __syncthreads();

        if (t < 32) {
            float lt = 0.f;
#pragma unroll
            for (int ww = 0; ww < 8; ++ww) lt += Lsh[ww * 32 + t];
            Linv[t] = 1.0f / lt;
        }
        if (ih == 0) {
            if (t < 64) bvs[t] = bv[t];
            const float4* wsrc = (const float4*)Wv;
            float4* wdst = (float4*)Wvs;
            wdst[t] = wsrc[t];
            wdst[t + 512] = wsrc[t + 512];
        }
        __syncthreads();

        // projection + residual for rows i0+ih*32 .. +31
        int i  = t & 31;
        int cg = t >> 5;
        float inv = Linv[i];
        float res[4] = {0.f, 0.f, 0.f, 0.f};
#pragma unroll 4
        for (int cb = 0; cb < 16; ++cb) {
            float4 oa = *(const float4*)(OshA + i * 68 + cb * 4);
            float4 ob = *(const float4*)(OshB + i * 68 + cb * 4);
            float4 o = make_float4(oa.x + ob.x, oa.y + ob.y, oa.z + ob.z, oa.w + ob.w);
#pragma unroll
            for (int k = 0; k < 4; ++k) {
                const float4 wv4 = *(const float4*)(Wvs + (cg * 4 + k) * 64 + cb * 4);
                res[k] = fmaf(wv4.x, o.x, fmaf(wv4.y, o.y, fmaf(wv4.z, o.z, fmaf(wv4.w, o.w, res[k]))));
            }
        }
#pragma unroll
        for (int k = 0; k < 4; ++k) {
            int cch = cg * 4 + k;
            float attn = fmaf(res[k], inv, bvs[cch]);
            size_t off = ((size_t)cch << 12) + (ih << 5) + i;
            outp[off] = fmaf(g, attn, xr[off]);
        }
    };

    epi(acc00, acc01, lsum0, 0);
    epi(acc10, acc11, lsum1, 1);
}

extern "C" void kernel_launch(void* const* d_in, const int* in_sizes, int n_in,
                              void* d_out, int out_size, void* d_ws, size_t ws_size,
                              hipStream_t stream) {
    const float* x     = (const float*)d_in[0];
    const float* Wq    = (const float*)d_in[1];
    const float* bq    = (const float*)d_in[2];
    const float* Wk    = (const float*)d_in[3];
    const float* bk    = (const float*)d_in[4];
    const float* Wv    = (const float*)d_in[5];
    const float* bv    = (const float*)d_in[6];
    const float* gamma = (const float*)d_in[7];
    float* out = (float*)d_out;

    // ws: qbf 256KB | kbf 256KB | xbf 2MB
    __hip_bfloat16* qbf = (__hip_bfloat16*)d_ws;
    __hip_bfloat16* kbf = qbf + (size_t)4 * NPIX * 8;
    __hip_bfloat16* xbf = kbf + (size_t)4 * NPIX * 8;

    prep_kernel<<<512, 512, 0, stream>>>(x, Wq, bq, Wk, bk, qbf, kbf, xbf);
    flash_fused_kernel<<<256, 512, 0, stream>>>(qbf, kbf, xbf, Wv, bv, x, gamma, out);
}